// Round 7
// baseline (450.521 us; speedup 1.0000x reference)
//
#include <hip/hip_runtime.h>
#include <hip/hip_bf16.h>
#include <cstdint>

#define ALPHA 8.3f

typedef __attribute__((ext_vector_type(8))) short bf16x8;
typedef __attribute__((ext_vector_type(4))) float f32x4;
typedef unsigned int u32;

// bf16 weights, layout [tap][o][c]  (9*128*128)
__device__ __align__(16) short g_wt[9 * 128 * 128];
// bf16 input, unit-major with zero halo: [b][hp][c16][wp][8 c-elems]
// hp,wp in [0,130), c16 in [0,16). One unit = 8 bf16 = 16 B.
__device__ __align__(16) short g_xt[(size_t)8 * 130 * 16 * 130 * 8];
// padded fp32 depth: [b][hp][wp]
__device__ float g_dp[8 * 130 * 130];

__device__ __forceinline__ short f2bf(float f) {
    union { float f; uint32_t u; } v; v.f = f;
    uint32_t r = v.u + 0x7fffu + ((v.u >> 16) & 1u);
    return (short)(r >> 16);
}

__device__ __forceinline__ size_t xt_off(int b, int hp, int c16, int wp) {
    // offset in shorts
    return ((((size_t)b * 130 + hp) * 16 + c16) * 130 + wp) * 8;
}

// Fused prep: weight transform + padded depth + x_t halo zero.
__global__ __launch_bounds__(256) void prep(const float* __restrict__ w,
                                            const float* __restrict__ depth) {
    int idx = blockIdx.x * 256 + threadIdx.x;
    if (idx < 147456) {                       // g_wt[tap][o][c]
        int c = idx & 127, o = (idx >> 7) & 127, tap = idx >> 14;
        g_wt[idx] = f2bf(w[(o * 128 + c) * 9 + tap]);
    } else if (idx < 147456 + 135200) {       // g_dp: 8*130*130
        int u = idx - 147456;
        int b = u / 16900; int rem = u - b * 16900;
        int hp = rem / 130, wp = rem - hp * 130;
        float v = 0.f;
        if (hp >= 1 && hp <= 128 && wp >= 1 && wp <= 128)
            v = depth[b * 16384 + (hp - 1) * 128 + (wp - 1)];
        g_dp[u] = v;
    } else if (idx < 147456 + 135200 + 66048) {  // x_t halo: 8 * 516 pos * 16
        int u = idx - (147456 + 135200);
        int b = u / 8256; int rem = u - b * 8256;
        int pos = rem >> 4, unit = rem & 15;
        int hp, wp;
        if (pos < 130)      { hp = 0;         wp = pos; }
        else if (pos < 260) { hp = 129;       wp = pos - 130; }
        else if (pos < 388) { hp = pos - 259; wp = 0; }
        else                { hp = pos - 387; wp = 129; }
        *reinterpret_cast<bf16x8*>(g_xt + xt_off(b, hp, unit, wp)) =
            (bf16x8){0, 0, 0, 0, 0, 0, 0, 0};
    }
}

// CHW fp32 -> unit-major bf16 via padded fp32 LDS tile. Block = one (b,h).
// Phase 1: coalesced fp32 reads (lane = w), LDS[w][c] stride 129 floats
//          -> bank = (w+c)&31, conflict-free writes.
// Phase 2: per-thread reads along c (lanes = w, conflict-free), f2bf pack,
//          store 16 B/lane, lanes consecutive w -> 1 KB contiguous stores.
__global__ __launch_bounds__(256) void x_transpose(const float* __restrict__ x) {
    __shared__ float T[128 * 129];             // 66048 B
    const int b = blockIdx.x >> 7;
    const int h = blockIdx.x & 127;
    const int tid = threadIdx.x;
    const int w = tid & 127;
    const int ch = tid >> 7;                   // c-half: 0..1

    const float* xb = x + ((size_t)(b * 128 + ch * 64)) * 16384 + h * 128 + w;
    #pragma unroll
    for (int k = 0; k < 64; ++k)
        T[w * 129 + ch * 64 + k] = xb[(size_t)k * 16384];
    __syncthreads();

    #pragma unroll
    for (int k = 0; k < 8; ++k) {
        int c16 = ch * 8 + k;
        const float* tr = T + w * 129 + c16 * 8;
        bf16x8 pk;
        #pragma unroll
        for (int i = 0; i < 8; ++i) pk[i] = f2bf(tr[i]);
        *reinterpret_cast<bf16x8*>(g_xt + xt_off(b, h + 1, c16, w + 1)) = pk;
    }
}

// Block = (b, h-pair, w-half): out[b][0:128][h0:h0+2][w0:w0+64].
// 512 threads, 8 waves: wave = (hsel, ohalf, wquarter) -> 64o x 32w x 1h.
// Stage 4 input rows x 66 w into LDS once (global_load_lds, source carries
// the inverse XOR swizzle), one barrier, then 9 taps:
//   per half-tap: batch-load 8 W-frags to regs, 2 ks x {2 ds_read + 8 MFMA},
//   then acc += sim_t[w] * P.
__global__ __launch_bounds__(512, 4) void depthconv_main(
    const float* __restrict__ bias, float* __restrict__ out)
{
    __shared__ __align__(16) short Xs[264 * 128];   // 67584 B
    __shared__ float simL[9][2][64];                // 4608 B

    const int blk = blockIdx.x;
    const int b = blk >> 7;
    const int rem = blk & 127;
    const int h0 = (rem >> 1) << 1;
    const int w0 = (rem & 1) << 6;

    const int tid = threadIdx.x;
    const int lane = tid & 63;
    const int wid = tid >> 6;          // 0..7
    const int hsel = wid >> 2;         // 0..1
    const int ohalf = (wid >> 1) & 1;  // 0..1
    const int wq = wid & 1;            // 0..1
    const int l15 = lane & 15;
    const int khi = lane >> 4;
    const int obase = ohalf << 6;
    char* xsp = (char*)Xs;

    // lane-resolved weight base: + tap*16384 + i*2048 + ks*32
    const short* wlane = g_wt + (obase + l15) * 128 + khi * 8;

    // ---- preload W(tap0, half0) into regs (independent of LDS)
    bf16x8 wreg[8];
    #pragma unroll
    for (int i = 0; i < 4; ++i)
        #pragma unroll
        for (int kk = 0; kk < 2; ++kk)
            wreg[i * 2 + kk] =
                *reinterpret_cast<const bf16x8*>(wlane + i * 2048 + kk * 32);

    // ---- stage 4224 units (4 rows x 66 w x 16 units), linear LDS dest,
    // source address carries the inverse XOR swizzle.
    #pragma unroll
    for (int iter = 0; iter < 9; ++iter) {
        int it = tid + iter * 512;
        if (it < 4224) {                  // wave-uniform (last: tids 0..127)
            int row = it >> 4;
            int u = it & 15;
            int r4 = row / 66;
            int wl = row - r4 * 66;
            int c16 = u ^ (row & 15);
            const short* src = g_xt + xt_off(b, h0 + r4, c16, w0 + wl);
            __builtin_amdgcn_global_load_lds(
                (const __attribute__((address_space(1))) u32*)src,
                (__attribute__((address_space(3))) u32*)(xsp + it * 16),
                16, 0, 0);
        }
    }

    // ---- sim table: simL[tap][hsel][wo]
    const float* dpb = g_dp + b * 16900;
    #pragma unroll
    for (int iter = 0; iter < 3; ++iter) {
        int idx = tid + iter * 512;
        if (idx < 1152) {
            int t = idx >> 7;
            int r2 = idx & 127;
            int hs = r2 >> 6;
            int wo = r2 & 63;
            int kh = t / 3, kw2 = t - 3 * kh;
            int ho = h0 + hs;
            float dc  = dpb[(ho + 1) * 130 + w0 + wo + 1];
            float dsv = dpb[(ho + kh) * 130 + w0 + wo + kw2];
            simL[t][hs][wo] = __expf(-ALPHA * fabsf(dc - dsv));
        }
    }
    __syncthreads();

    f32x4 acc[4][2];
    #pragma unroll
    for (int i = 0; i < 4; ++i)
        #pragma unroll
        for (int j = 0; j < 2; ++j)
            acc[i][j] = (f32x4){0.f, 0.f, 0.f, 0.f};

    const f32x4 z4 = (f32x4){0.f, 0.f, 0.f, 0.f};

    #pragma unroll
    for (int tap = 0; tap < 9; ++tap) {
        const int r = tap / 3;
        const int kw = tap - 3 * r;
        const int rowb = (hsel + r) * 66 + wq * 32 + l15 + kw;

        f32x4 P[4][2];

        #pragma unroll
        for (int half = 0; half < 2; ++half) {
            #pragma unroll
            for (int kk = 0; kk < 2; ++kk) {
                const int ks = half * 2 + kk;
                const int cb = ks * 32 + khi * 8;
                bf16x8 bfr[2];
                #pragma unroll
                for (int j = 0; j < 2; ++j) {
                    int row = rowb + j * 16;
                    int byte = (row << 8) | ((cb << 1) ^ ((row & 15) << 4));
                    bfr[j] = *reinterpret_cast<const bf16x8*>(xsp + byte);
                }
                #pragma unroll
                for (int i = 0; i < 4; ++i)
                    #pragma unroll
                    for (int j = 0; j < 2; ++j)
                        P[i][j] = __builtin_amdgcn_mfma_f32_16x16x32_bf16(
                            wreg[i * 2 + kk], bfr[j],
                            (half == 0 && kk == 0) ? z4 : P[i][j], 0, 0, 0);
            }
            // re-issue W batch: half0 -> load half1; half1 -> load next tap half0
            if (half == 0) {
                #pragma unroll
                for (int i = 0; i < 4; ++i)
                    #pragma unroll
                    for (int kk = 0; kk < 2; ++kk)
                        wreg[i * 2 + kk] = *reinterpret_cast<const bf16x8*>(
                            wlane + tap * 16384 + i * 2048 + 64 + kk * 32);
            } else if (tap < 8) {
                #pragma unroll
                for (int i = 0; i < 4; ++i)
                    #pragma unroll
                    for (int kk = 0; kk < 2; ++kk)
                        wreg[i * 2 + kk] = *reinterpret_cast<const bf16x8*>(
                            wlane + (tap + 1) * 16384 + i * 2048 + kk * 32);
            }
        }

        float sv0 = simL[tap][hsel][wq * 32 + l15];
        float sv1 = simL[tap][hsel][wq * 32 + 16 + l15];
        #pragma unroll
        for (int i = 0; i < 4; ++i)
            #pragma unroll
            for (int rr = 0; rr < 4; ++rr) {
                acc[i][0][rr] += sv0 * P[i][0][rr];
                acc[i][1][rr] += sv1 * P[i][1][rr];
            }
    }

    // ---- epilogue
    #pragma unroll
    for (int i = 0; i < 4; ++i) {
        #pragma unroll
        for (int rr = 0; rr < 4; ++rr) {
            const int o = obase + i * 16 + (khi << 2) + rr;
            const float bv = bias[o];
            float* orow = out + (((size_t)(b * 128 + o)) * 128 + (h0 + hsel)) * 128
                          + w0 + wq * 32;
            orow[l15] = acc[i][0][rr] + bv;
            orow[16 + l15] = acc[i][1][rr] + bv;
        }
    }
}

extern "C" void kernel_launch(void* const* d_in, const int* in_sizes, int n_in,
                              void* d_out, int out_size, void* d_ws, size_t ws_size,
                              hipStream_t stream) {
    const float* x     = (const float*)d_in[0];
    const float* depth = (const float*)d_in[1];
    const float* wgt   = (const float*)d_in[2];
    const float* bias  = (const float*)d_in[3];
    float* out = (float*)d_out;

    hipLaunchKernelGGL(prep, dim3(1363), dim3(256), 0, stream, wgt, depth);
    hipLaunchKernelGGL(x_transpose, dim3(8 * 128), dim3(256), 0, stream, x);
    hipLaunchKernelGGL(depthconv_main, dim3(8 * 64 * 2), dim3(512), 0, stream,
                       bias, out);
}